// Round 1
// baseline (320.502 us; speedup 1.0000x reference)
//
#include <hip/hip_runtime.h>

#define K_CLUSTERS 512
#define D_FEAT 64
#define ROWS_PER_BLOCK 64
#define THREADS 256

typedef short bf16x8 __attribute__((ext_vector_type(8)));
typedef float f32x4 __attribute__((ext_vector_type(4)));

__device__ __forceinline__ unsigned short f32_to_bf16(float f) {
  unsigned int u = __float_as_uint(f);
  u += 0x7fffu + ((u >> 16) & 1u);   // RNE
  return (unsigned short)(u >> 16);
}
__device__ __forceinline__ float bf16_to_f32(unsigned short h) {
  return __uint_as_float(((unsigned int)h) << 16);
}

// ---------------- prep: split centroids into hi/lo bf16, both layouts, + scaled |c|^2
__global__ void kmeans_prep(const float* __restrict__ cent,
                            unsigned short* __restrict__ chi,   // [K][D]
                            unsigned short* __restrict__ clo,   // [K][D]
                            unsigned short* __restrict__ cthi,  // [D][K]
                            unsigned short* __restrict__ ctlo,  // [D][K]
                            float* __restrict__ csqs) {         // [K], 10*log2e*|c|^2
  int k = blockIdx.x * blockDim.x + threadIdx.x;
  if (k >= K_CLUSTERS) return;
  float s = 0.f;
  for (int f = 0; f < D_FEAT; ++f) {
    float v = cent[k * D_FEAT + f];
    s += v * v;
    unsigned short h = f32_to_bf16(v);
    float rem = v - bf16_to_f32(h);
    unsigned short l = f32_to_bf16(rem);
    chi[k * D_FEAT + f] = h;
    clo[k * D_FEAT + f] = l;
    cthi[f * K_CLUSTERS + k] = h;
    ctlo[f * K_CLUSTERS + k] = l;
  }
  csqs[k] = s * 14.42695040888963f;  // 10 * log2(e)
}

// ---------------- main fused kernel: 64 rows/block, 16 rows/wave
__global__ __launch_bounds__(THREADS, 2) void kmeans_main(
    const float* __restrict__ x,
    const unsigned short* __restrict__ chi,
    const unsigned short* __restrict__ clo,
    const unsigned short* __restrict__ cthi,
    const unsigned short* __restrict__ ctlo,
    const float* __restrict__ csqs,
    float* __restrict__ out) {
  // 64 KB static LDS. xh/xl (staging, 18432 B) alias the head of W (65536 B);
  // barrier after A-frag loads makes the overwrite safe.
  __shared__ __attribute__((aligned(16))) unsigned char smem[65536];
  unsigned short* xh = (unsigned short*)smem;        // [64][72] bf16 (padded)
  unsigned short* xl = xh + 64 * 72;                 // [64][72]
  unsigned short* W  = (unsigned short*)smem;        // [4 waves][16][512] bf16, XOR-swizzled

  const int tid  = threadIdx.x;
  const int wv   = tid >> 6;
  const int lane = tid & 63;
  const int l16  = lane & 15;
  const int quad = lane >> 4;
  const long long rowbase = (long long)blockIdx.x * ROWS_PER_BLOCK;

  // ---- stage x -> xh/xl (coalesced float4 loads, hi/lo bf16 split) ----
  {
    int r  = tid >> 2;             // 0..63
    int f0 = (tid & 3) * 16;       // 0,16,32,48
    const float4* src4 = (const float4*)(x + (rowbase + r) * D_FEAT + f0);
#pragma unroll
    for (int i = 0; i < 4; ++i) {
      float4 v = src4[i];
      float vv[4] = {v.x, v.y, v.z, v.w};
#pragma unroll
      for (int j = 0; j < 4; ++j) {
        unsigned short h = f32_to_bf16(vv[j]);
        xh[r * 72 + f0 + i * 4 + j] = h;
        xl[r * 72 + f0 + i * 4 + j] = f32_to_bf16(vv[j] - bf16_to_f32(h));
      }
    }
  }
  __syncthreads();

  // ---- A fragments (loop-invariant): A[m=l16][k=quad*8+j], rows wv*16+l16 ----
  bf16x8 ah[2], al[2];
#pragma unroll
  for (int ks = 0; ks < 2; ++ks) {
    ah[ks] = *(const bf16x8*)(xh + (wv * 16 + l16) * 72 + ks * 32 + quad * 8);
    al[ks] = *(const bf16x8*)(xl + (wv * 16 + l16) * 72 + ks * 32 + quad * 8);
  }
  __syncthreads();   // xh/xl now dead -> W region writable

  // ---- Phase A: cross GEMM, logits into 128 register accs (16 rows x 512 cl) ----
  // logit' = 20*log2e*cross - 10*log2e*|c|^2   (x^2 term cancels in softmax)
  f32x4 acc[32];
  const int bko = quad * 8;
#pragma unroll
  for (int t = 0; t < 32; ++t) {
    int cluster = t * 16 + l16;
    bf16x8 bh0 = *(const bf16x8*)(chi + cluster * 64 + bko);
    bf16x8 bh1 = *(const bf16x8*)(chi + cluster * 64 + 32 + bko);
    bf16x8 bl0 = *(const bf16x8*)(clo + cluster * 64 + bko);
    bf16x8 bl1 = *(const bf16x8*)(clo + cluster * 64 + 32 + bko);
    float cs = csqs[cluster];
    f32x4 hhv = {0.f, 0.f, 0.f, 0.f};
    f32x4 mix = {0.f, 0.f, 0.f, 0.f};
    hhv = __builtin_amdgcn_mfma_f32_16x16x32_bf16(ah[0], bh0, hhv, 0, 0, 0);
    hhv = __builtin_amdgcn_mfma_f32_16x16x32_bf16(ah[1], bh1, hhv, 0, 0, 0);
    mix = __builtin_amdgcn_mfma_f32_16x16x32_bf16(ah[0], bl0, mix, 0, 0, 0);
    mix = __builtin_amdgcn_mfma_f32_16x16x32_bf16(ah[1], bl1, mix, 0, 0, 0);
    mix = __builtin_amdgcn_mfma_f32_16x16x32_bf16(al[0], bh0, mix, 0, 0, 0);
    mix = __builtin_amdgcn_mfma_f32_16x16x32_bf16(al[1], bh1, mix, 0, 0, 0);
#pragma unroll
    for (int r = 0; r < 4; ++r)
      acc[t][r] = 28.85390081777927f * (hhv[r] + mix[r]) - cs;
  }

  // ---- Phase B: in-register softmax (rows quad*4+r live in 16-lane quad group) ----
  float mrow[4] = {-1e30f, -1e30f, -1e30f, -1e30f};
#pragma unroll
  for (int t = 0; t < 32; ++t)
#pragma unroll
    for (int r = 0; r < 4; ++r) mrow[r] = fmaxf(mrow[r], acc[t][r]);
#pragma unroll
  for (int d = 1; d < 16; d <<= 1)
#pragma unroll
    for (int r = 0; r < 4; ++r) mrow[r] = fmaxf(mrow[r], __shfl_xor(mrow[r], d, 64));

  float srow[4] = {0.f, 0.f, 0.f, 0.f};
#pragma unroll
  for (int t = 0; t < 32; ++t)
#pragma unroll
    for (int r = 0; r < 4; ++r) {
      float e = exp2f(acc[t][r] - mrow[r]);   // native v_exp_f32
      acc[t][r] = e;
      srow[r] += e;
    }
#pragma unroll
  for (int d = 1; d < 16; d <<= 1)
#pragma unroll
    for (int r = 0; r < 4; ++r) srow[r] += __shfl_xor(srow[r], d, 64);

  // ---- write W (unnormalized weights) as bf16 into XOR-swizzled LDS ----
  unsigned short* Wmy = W + wv * (16 * 512);
#pragma unroll
  for (int t = 0; t < 32; ++t) {
    int c  = t * 16 + l16;
    int kb = c >> 3;
    int jj = c & 7;
#pragma unroll
    for (int r = 0; r < 4; ++r) {
      int row = quad * 4 + r;
      Wmy[row * 512 + ((kb ^ row) << 3) + jj] = f32_to_bf16(acc[t][r]);
    }
  }
  __syncthreads();   // cross-lane LDS visibility before A-frag reads

  // ---- Phase C: out = W @ (chi + clo), 16 rows x 64 feats per wave ----
  f32x4 oh[4], ol[4];
#pragma unroll
  for (int ct = 0; ct < 4; ++ct) {
    oh[ct] = (f32x4){0.f, 0.f, 0.f, 0.f};
    ol[ct] = (f32x4){0.f, 0.f, 0.f, 0.f};
  }
#pragma unroll
  for (int ks = 0; ks < 16; ++ks) {
    int kb = ((ks * 4 + quad) ^ l16) << 3;
    bf16x8 aw = *(const bf16x8*)(Wmy + l16 * 512 + kb);
#pragma unroll
    for (int ct = 0; ct < 4; ++ct) {
      int feat = ct * 16 + l16;
      bf16x8 bh = *(const bf16x8*)(cthi + feat * K_CLUSTERS + ks * 32 + quad * 8);
      bf16x8 bl = *(const bf16x8*)(ctlo + feat * K_CLUSTERS + ks * 32 + quad * 8);
      oh[ct] = __builtin_amdgcn_mfma_f32_16x16x32_bf16(aw, bh, oh[ct], 0, 0, 0);
      ol[ct] = __builtin_amdgcn_mfma_f32_16x16x32_bf16(aw, bl, ol[ct], 0, 0, 0);
    }
  }

  // ---- epilogue: normalize by row sum, store ----
  float inv[4];
#pragma unroll
  for (int r = 0; r < 4; ++r) inv[r] = 1.0f / srow[r];
  float* obase = out + (rowbase + wv * 16) * D_FEAT;
#pragma unroll
  for (int ct = 0; ct < 4; ++ct) {
    f32x4 o = oh[ct] + ol[ct];
#pragma unroll
    for (int r = 0; r < 4; ++r) {
      int row = quad * 4 + r;
      obase[row * D_FEAT + ct * 16 + l16] = o[r] * inv[r];
    }
  }
}

extern "C" void kernel_launch(void* const* d_in, const int* in_sizes, int n_in,
                              void* d_out, int out_size, void* d_ws, size_t ws_size,
                              hipStream_t stream) {
  const float* x    = (const float*)d_in[0];
  const float* cent = (const float*)d_in[1];
  float* out        = (float*)d_out;

  unsigned short* chi  = (unsigned short*)d_ws;
  unsigned short* clo  = chi  + K_CLUSTERS * D_FEAT;
  unsigned short* cthi = clo  + K_CLUSTERS * D_FEAT;
  unsigned short* ctlo = cthi + K_CLUSTERS * D_FEAT;
  float*          csqs = (float*)(ctlo + K_CLUSTERS * D_FEAT);

  kmeans_prep<<<(K_CLUSTERS + THREADS - 1) / THREADS, THREADS, 0, stream>>>(
      cent, chi, clo, cthi, ctlo, csqs);

  int nrows = in_sizes[0] / D_FEAT;  // 131072
  kmeans_main<<<nrows / ROWS_PER_BLOCK, THREADS, 0, stream>>>(
      x, chi, clo, cthi, ctlo, csqs, out);
}

// Round 2
// 313.858 us; speedup vs baseline: 1.0212x; 1.0212x over previous
//
#include <hip/hip_runtime.h>

#define K_CLUSTERS 512
#define D_FEAT 64
#define ROWS_PER_BLOCK 16
#define THREADS 256

typedef short bf16x8 __attribute__((ext_vector_type(8)));
typedef short bf16x4 __attribute__((ext_vector_type(4)));
typedef float f32x4 __attribute__((ext_vector_type(4)));

__device__ __forceinline__ unsigned short f32_to_bf16(float f) {
  unsigned int u = __float_as_uint(f);
  u += 0x7fffu + ((u >> 16) & 1u);   // RNE
  return (unsigned short)(u >> 16);
}
__device__ __forceinline__ float bf16_to_f32(unsigned short h) {
  return __uint_as_float(((unsigned int)h) << 16);
}

// ---------------- prep: split centroids into hi/lo bf16, both layouts, + scaled |c|^2
__global__ void kmeans_prep(const float* __restrict__ cent,
                            unsigned short* __restrict__ chi,   // [K][D]
                            unsigned short* __restrict__ clo,   // [K][D]
                            unsigned short* __restrict__ cthi,  // [D][K]
                            unsigned short* __restrict__ ctlo,  // [D][K]
                            float* __restrict__ csqs) {         // [K], 10*log2e*|c|^2
  int k = blockIdx.x * blockDim.x + threadIdx.x;
  if (k >= K_CLUSTERS) return;
  float s = 0.f;
  for (int f = 0; f < D_FEAT; ++f) {
    float v = cent[k * D_FEAT + f];
    s += v * v;
    unsigned short h = f32_to_bf16(v);
    float rem = v - bf16_to_f32(h);
    unsigned short l = f32_to_bf16(rem);
    chi[k * D_FEAT + f] = h;
    clo[k * D_FEAT + f] = l;
    cthi[f * K_CLUSTERS + k] = h;
    ctlo[f * K_CLUSTERS + k] = l;
  }
  csqs[k] = s * 14.42695040888963f;  // 10 * log2(e)
}

// ---------------- main fused kernel: 16 rows/block; Phase A cluster-split,
// Phase C feature-split across the 4 waves. Small LDS (17.4 KB) + small acc
// (32 VGPR) -> high occupancy + pipelineable loads.
__global__ __launch_bounds__(THREADS, 4) void kmeans_main(
    const float* __restrict__ x,
    const unsigned short* __restrict__ chi,
    const unsigned short* __restrict__ clo,
    const unsigned short* __restrict__ cthi,
    const unsigned short* __restrict__ ctlo,
    const float* __restrict__ csqs,
    float* __restrict__ out) {
  // LDS: W [16][512] bf16 (16384 B, XOR-swizzled) + redmax [16][4] f32 (256B)
  // + redsum [16][4] f32 (256B) + pad. x staging (xh/xl, 16x72 bf16 each,
  // 4608 B) aliases the head of W: A-frags are read before the Phase-A
  // barrier; W writes happen after it.
  __shared__ __attribute__((aligned(16))) unsigned char smem[16384 + 1024];
  unsigned short* xh = (unsigned short*)smem;            // [16][72]
  unsigned short* xl = xh + 16 * 72;                     // [16][72]
  unsigned short* W  = (unsigned short*)smem;            // [16][512] swizzled
  float* redmax = (float*)(smem + 16384);                // [16][4]
  float* redsum = (float*)(smem + 16384 + 256);          // [16][4]

  const int tid  = threadIdx.x;
  const int wv   = tid >> 6;
  const int lane = tid & 63;
  const int l16  = lane & 15;
  const int quad = lane >> 4;
  const long long rowbase = (long long)blockIdx.x * ROWS_PER_BLOCK;

  // ---- stage x -> xh/xl (coalesced float4 loads, hi/lo bf16 split) ----
  {
    int r  = tid >> 4;            // 0..15
    int f0 = (tid & 15) * 4;      // 0..60
    float4 v = *(const float4*)(x + (rowbase + r) * D_FEAT + f0);
    float vv[4] = {v.x, v.y, v.z, v.w};
    bf16x4 hi, lo;
#pragma unroll
    for (int j = 0; j < 4; ++j) {
      unsigned short h = f32_to_bf16(vv[j]);
      hi[j] = (short)h;
      lo[j] = (short)f32_to_bf16(vv[j] - bf16_to_f32(h));
    }
    *(bf16x4*)(xh + r * 72 + f0) = hi;
    *(bf16x4*)(xl + r * 72 + f0) = lo;
  }
  __syncthreads();

  // ---- A fragments (identical across waves): A[m=l16][k=quad*8+j+32ks] ----
  bf16x8 ah[2], al[2];
#pragma unroll
  for (int ks = 0; ks < 2; ++ks) {
    ah[ks] = *(const bf16x8*)(xh + l16 * 72 + ks * 32 + quad * 8);
    al[ks] = *(const bf16x8*)(xl + l16 * 72 + ks * 32 + quad * 8);
  }

  // ---- Phase A: this wave's 128-cluster slice, 16 rows. acc = 32 VGPRs ----
  // logit' = 20*log2e*cross - 10*log2e*|c|^2  (x^2 row-constant cancels)
  const int cbase = wv * 128;
  const int bko = quad * 8;
  f32x4 acc[8];
#pragma unroll
  for (int t = 0; t < 8; ++t) {
    int cluster = cbase + t * 16 + l16;
    bf16x8 bh0 = *(const bf16x8*)(chi + cluster * 64 + bko);
    bf16x8 bh1 = *(const bf16x8*)(chi + cluster * 64 + 32 + bko);
    bf16x8 bl0 = *(const bf16x8*)(clo + cluster * 64 + bko);
    bf16x8 bl1 = *(const bf16x8*)(clo + cluster * 64 + 32 + bko);
    float cs = csqs[cluster];
    f32x4 hhv = {0.f, 0.f, 0.f, 0.f};
    f32x4 mix = {0.f, 0.f, 0.f, 0.f};
    hhv = __builtin_amdgcn_mfma_f32_16x16x32_bf16(ah[0], bh0, hhv, 0, 0, 0);
    hhv = __builtin_amdgcn_mfma_f32_16x16x32_bf16(ah[1], bh1, hhv, 0, 0, 0);
    mix = __builtin_amdgcn_mfma_f32_16x16x32_bf16(ah[0], bl0, mix, 0, 0, 0);
    mix = __builtin_amdgcn_mfma_f32_16x16x32_bf16(ah[1], bl1, mix, 0, 0, 0);
    mix = __builtin_amdgcn_mfma_f32_16x16x32_bf16(al[0], bh0, mix, 0, 0, 0);
    mix = __builtin_amdgcn_mfma_f32_16x16x32_bf16(al[1], bh1, mix, 0, 0, 0);
#pragma unroll
    for (int r = 0; r < 4; ++r)
      acc[t][r] = 28.85390081777927f * (hhv[r] + mix[r]) - cs;
  }

  // ---- local (per-wave) row max over 128 clusters ----
  float mrow[4] = {-1e30f, -1e30f, -1e30f, -1e30f};
#pragma unroll
  for (int t = 0; t < 8; ++t)
#pragma unroll
    for (int r = 0; r < 4; ++r) mrow[r] = fmaxf(mrow[r], acc[t][r]);
#pragma unroll
  for (int d = 1; d < 16; d <<= 1)
#pragma unroll
    for (int r = 0; r < 4; ++r) mrow[r] = fmaxf(mrow[r], __shfl_xor(mrow[r], d, 64));
  if (l16 == 0) {
#pragma unroll
    for (int r = 0; r < 4; ++r) redmax[(quad * 4 + r) * 4 + wv] = mrow[r];
  }
  __syncthreads();

  // ---- global row max, exp, local sums ----
  float gmax[4];
#pragma unroll
  for (int r = 0; r < 4; ++r) {
    f32x4 m4 = *(const f32x4*)(redmax + (quad * 4 + r) * 4);
    gmax[r] = fmaxf(fmaxf(m4[0], m4[1]), fmaxf(m4[2], m4[3]));
  }
  float srow[4] = {0.f, 0.f, 0.f, 0.f};
#pragma unroll
  for (int t = 0; t < 8; ++t)
#pragma unroll
    for (int r = 0; r < 4; ++r) {
      float e = exp2f(acc[t][r] - gmax[r]);   // native v_exp_f32
      acc[t][r] = e;
      srow[r] += e;
    }
#pragma unroll
  for (int d = 1; d < 16; d <<= 1)
#pragma unroll
    for (int r = 0; r < 4; ++r) srow[r] += __shfl_xor(srow[r], d, 64);
  if (l16 == 0) {
#pragma unroll
    for (int r = 0; r < 4; ++r) redsum[(quad * 4 + r) * 4 + wv] = srow[r];
  }

  // ---- write W slice (unnormalized weights, bf16) XOR-swizzled ----
#pragma unroll
  for (int t = 0; t < 8; ++t) {
    int c  = cbase + t * 16 + l16;
    int kb = c >> 3;
    int jj = c & 7;
#pragma unroll
    for (int r = 0; r < 4; ++r) {
      int row = quad * 4 + r;
      W[row * 512 + ((kb ^ (row & 7)) << 3) + jj] = f32_to_bf16(acc[t][r]);
    }
  }
  __syncthreads();   // W + redsum visible

  // ---- global row sums ----
  float gsum[4];
#pragma unroll
  for (int r = 0; r < 4; ++r) {
    f32x4 s4 = *(const f32x4*)(redsum + (quad * 4 + r) * 4);
    gsum[r] = (s4[0] + s4[1]) + (s4[2] + s4[3]);
  }

  // ---- Phase C: this wave's 16-feature slice, full K=512 ----
  const int fbase = wv * 16;
  f32x4 oh = {0.f, 0.f, 0.f, 0.f};
  f32x4 ol = {0.f, 0.f, 0.f, 0.f};
#pragma unroll
  for (int ks = 0; ks < 16; ++ks) {
    int kb = ((ks * 4 + quad) ^ (l16 & 7)) << 3;
    bf16x8 aw = *(const bf16x8*)(W + l16 * 512 + kb);
    bf16x8 bh = *(const bf16x8*)(cthi + (fbase + l16) * K_CLUSTERS + ks * 32 + quad * 8);
    bf16x8 bl = *(const bf16x8*)(ctlo + (fbase + l16) * K_CLUSTERS + ks * 32 + quad * 8);
    oh = __builtin_amdgcn_mfma_f32_16x16x32_bf16(aw, bh, oh, 0, 0, 0);
    ol = __builtin_amdgcn_mfma_f32_16x16x32_bf16(aw, bl, ol, 0, 0, 0);
  }

  // ---- epilogue: normalize by row sum, store 16x16 tile ----
  float* obase = out + rowbase * D_FEAT + fbase + l16;
#pragma unroll
  for (int r = 0; r < 4; ++r) {
    int row = quad * 4 + r;
    obase[row * D_FEAT] = (oh[r] + ol[r]) / gsum[r];
  }
}

extern "C" void kernel_launch(void* const* d_in, const int* in_sizes, int n_in,
                              void* d_out, int out_size, void* d_ws, size_t ws_size,
                              hipStream_t stream) {
  const float* x    = (const float*)d_in[0];
  const float* cent = (const float*)d_in[1];
  float* out        = (float*)d_out;

  unsigned short* chi  = (unsigned short*)d_ws;
  unsigned short* clo  = chi  + K_CLUSTERS * D_FEAT;
  unsigned short* cthi = clo  + K_CLUSTERS * D_FEAT;
  unsigned short* ctlo = cthi + K_CLUSTERS * D_FEAT;
  float*          csqs = (float*)(ctlo + K_CLUSTERS * D_FEAT);

  kmeans_prep<<<(K_CLUSTERS + THREADS - 1) / THREADS, THREADS, 0, stream>>>(
      cent, chi, clo, cthi, ctlo, csqs);

  int nrows = in_sizes[0] / D_FEAT;  // 131072
  kmeans_main<<<nrows / ROWS_PER_BLOCK, THREADS, 0, stream>>>(
      x, chi, clo, cthi, ctlo, csqs, out);
}

// Round 3
// 152.550 us; speedup vs baseline: 2.1010x; 2.0574x over previous
//
#include <hip/hip_runtime.h>

#define K_CLUSTERS 512
#define D_FEAT 64
#define ROWS_PER_BLOCK 64
#define THREADS 256

typedef short bf16x8 __attribute__((ext_vector_type(8)));
typedef short bf16x4 __attribute__((ext_vector_type(4)));
typedef float f32x4 __attribute__((ext_vector_type(4)));

__device__ __forceinline__ unsigned short f32_to_bf16(float f) {
  unsigned int u = __float_as_uint(f);
  u += 0x7fffu + ((u >> 16) & 1u);   // RNE
  return (unsigned short)(u >> 16);
}
__device__ __forceinline__ float bf16_to_f32(unsigned short h) {
  return __uint_as_float(((unsigned int)h) << 16);
}

// ---------------- prep: split centroids into hi/lo bf16, both layouts, + scaled |c|^2
__global__ void kmeans_prep(const float* __restrict__ cent,
                            unsigned short* __restrict__ chi,   // [K][D]
                            unsigned short* __restrict__ clo,   // [K][D]
                            unsigned short* __restrict__ cthi,  // [D][K]
                            unsigned short* __restrict__ ctlo,  // [D][K]
                            float* __restrict__ csqs) {         // [K], 10*log2e*|c|^2
  int k = blockIdx.x * blockDim.x + threadIdx.x;
  if (k >= K_CLUSTERS) return;
  float s = 0.f;
  for (int f = 0; f < D_FEAT; ++f) {
    float v = cent[k * D_FEAT + f];
    s += v * v;
    unsigned short h = f32_to_bf16(v);
    float rem = v - bf16_to_f32(h);
    unsigned short l = f32_to_bf16(rem);
    chi[k * D_FEAT + f] = h;
    clo[k * D_FEAT + f] = l;
    cthi[f * K_CLUSTERS + k] = h;
    ctlo[f * K_CLUSTERS + k] = l;
  }
  csqs[k] = s * 14.42695040888963f;  // 10 * log2(e)
}

// ---------------- main fused kernel: 64 rows/block.
// Phase A: cluster-split (wave w owns 128 clusters, all 4 row-tiles); B-frags
// loaded once, weights exp'd + written to LDS streaming (no 128-reg acc).
// No max-subtraction: logits bounded (|logit| < ~80), exp2/f32/bf16 hold them.
// Phase C: feature-split (wave w owns 16 feats), W read back from swizzled LDS.
__global__ __launch_bounds__(THREADS, 2) void kmeans_main(
    const float* __restrict__ x,
    const unsigned short* __restrict__ chi,
    const unsigned short* __restrict__ clo,
    const unsigned short* __restrict__ cthi,
    const unsigned short* __restrict__ ctlo,
    const float* __restrict__ csqs,
    float* __restrict__ out) {
  // LDS: W [64][512] bf16 (65536 B, XOR swizzle c ^ ((row>>2&3)<<4)).
  // x staging xh/xl [64][72] (18432 B) aliases head of W (dead after A-frag
  // loads, fenced by barrier 2). redsum [64][4] f32 after W.
  __shared__ __attribute__((aligned(16))) unsigned char smem[65536 + 1024];
  unsigned short* xh = (unsigned short*)smem;            // [64][72]
  unsigned short* xl = xh + 64 * 72;                     // [64][72]
  unsigned short* W  = (unsigned short*)smem;            // [64][512] swizzled
  float* redsum = (float*)(smem + 65536);                // [64][4]

  const int tid  = threadIdx.x;
  const int wv   = tid >> 6;
  const int lane = tid & 63;
  const int l16  = lane & 15;
  const int quad = lane >> 4;
  const long long rowbase = (long long)blockIdx.x * ROWS_PER_BLOCK;

  // ---- stage x -> xh/xl (coalesced float4 loads, hi/lo bf16 split) ----
  {
    int r  = tid >> 2;             // 0..63
    int f0 = (tid & 3) * 16;       // 0,16,32,48
    const float4* src4 = (const float4*)(x + (rowbase + r) * D_FEAT + f0);
#pragma unroll
    for (int i = 0; i < 4; ++i) {
      float4 v = src4[i];
      float vv[4] = {v.x, v.y, v.z, v.w};
      bf16x4 hi, lo;
#pragma unroll
      for (int j = 0; j < 4; ++j) {
        unsigned short h = f32_to_bf16(vv[j]);
        hi[j] = (short)h;
        lo[j] = (short)f32_to_bf16(vv[j] - bf16_to_f32(h));
      }
      *(bf16x4*)(xh + r * 72 + f0 + i * 4) = hi;
      *(bf16x4*)(xl + r * 72 + f0 + i * 4) = lo;
    }
  }
  __syncthreads();   // staging visible

  // ---- A fragments for all 4 row-tiles: A[m=l16][k=quad*8+j], 64 VGPRs ----
  bf16x8 ah[4][2], al[4][2];
#pragma unroll
  for (int rt = 0; rt < 4; ++rt)
#pragma unroll
    for (int ks = 0; ks < 2; ++ks) {
      ah[rt][ks] = *(const bf16x8*)(xh + (rt * 16 + l16) * 72 + ks * 32 + quad * 8);
      al[rt][ks] = *(const bf16x8*)(xl + (rt * 16 + l16) * 72 + ks * 32 + quad * 8);
    }
  __syncthreads();   // xh/xl dead -> W region writable

  // ---- Phase A: this wave's 128-cluster slice x 64 rows, streaming ----
  const int cbase = wv * 128;
  const int bko = quad * 8;
  f32x4 srow[4] = {{0.f,0.f,0.f,0.f},{0.f,0.f,0.f,0.f},{0.f,0.f,0.f,0.f},{0.f,0.f,0.f,0.f}};

  // prefetch t=0
  bf16x8 bh0 = *(const bf16x8*)(chi + (cbase + l16) * 64 + bko);
  bf16x8 bh1 = *(const bf16x8*)(chi + (cbase + l16) * 64 + 32 + bko);
  bf16x8 bl0 = *(const bf16x8*)(clo + (cbase + l16) * 64 + bko);
  bf16x8 bl1 = *(const bf16x8*)(clo + (cbase + l16) * 64 + 32 + bko);
  float cs = csqs[cbase + l16];

#pragma unroll
  for (int t = 0; t < 8; ++t) {
    bf16x8 cbh0 = bh0, cbh1 = bh1, cbl0 = bl0, cbl1 = bl1;
    float ccs = cs;
    if (t < 7) {   // prefetch t+1
      int cl = cbase + (t + 1) * 16 + l16;
      bh0 = *(const bf16x8*)(chi + cl * 64 + bko);
      bh1 = *(const bf16x8*)(chi + cl * 64 + 32 + bko);
      bl0 = *(const bf16x8*)(clo + cl * 64 + bko);
      bl1 = *(const bf16x8*)(clo + cl * 64 + 32 + bko);
      cs = csqs[cl];
    }
    const int c = cbase + t * 16 + l16;
#pragma unroll
    for (int rt = 0; rt < 4; ++rt) {
      f32x4 a = {0.f, 0.f, 0.f, 0.f};
      a = __builtin_amdgcn_mfma_f32_16x16x32_bf16(ah[rt][0], cbh0, a, 0, 0, 0);
      a = __builtin_amdgcn_mfma_f32_16x16x32_bf16(ah[rt][1], cbh1, a, 0, 0, 0);
      a = __builtin_amdgcn_mfma_f32_16x16x32_bf16(ah[rt][0], cbl0, a, 0, 0, 0);
      a = __builtin_amdgcn_mfma_f32_16x16x32_bf16(ah[rt][1], cbl1, a, 0, 0, 0);
      a = __builtin_amdgcn_mfma_f32_16x16x32_bf16(al[rt][0], cbh0, a, 0, 0, 0);
      a = __builtin_amdgcn_mfma_f32_16x16x32_bf16(al[rt][1], cbh1, a, 0, 0, 0);
      // weight = 2^(20*log2e*cross - 10*log2e*|c|^2); row const 2^(-10le*x^2) cancels
#pragma unroll
      for (int r = 0; r < 4; ++r) {
        float e = exp2f(fmaf(28.85390081777927f, a[r], -ccs));
        srow[rt][r] += e;
        int row = rt * 16 + quad * 4 + r;
        W[row * 512 + (c ^ ((((unsigned)row >> 2) & 3) << 4))] = f32_to_bf16(e);
      }
    }
  }

  // ---- per-wave partial row sums -> LDS ----
#pragma unroll
  for (int d = 1; d < 16; d <<= 1)
#pragma unroll
    for (int rt = 0; rt < 4; ++rt)
#pragma unroll
      for (int r = 0; r < 4; ++r) srow[rt][r] += __shfl_xor(srow[rt][r], d, 64);
  if (l16 == 0) {
#pragma unroll
    for (int rt = 0; rt < 4; ++rt)
#pragma unroll
      for (int r = 0; r < 4; ++r)
        redsum[(rt * 16 + quad * 4 + r) * 4 + wv] = srow[rt][r];
  }
  __syncthreads();   // W + redsum visible to all waves

  // ---- reciprocal row sums (broadcast LDS reads) ----
  float inv[4][4];
#pragma unroll
  for (int rt = 0; rt < 4; ++rt)
#pragma unroll
    for (int r = 0; r < 4; ++r) {
      f32x4 s4 = *(const f32x4*)(redsum + (rt * 16 + quad * 4 + r) * 4);
      inv[rt][r] = __builtin_amdgcn_rcpf((s4[0] + s4[1]) + (s4[2] + s4[3]));
    }

  // ---- Phase C: this wave's 16-feature slice, full K=512, 4 row-tiles ----
  const int feat = wv * 16 + l16;
  f32x4 oacc[4] = {{0.f,0.f,0.f,0.f},{0.f,0.f,0.f,0.f},{0.f,0.f,0.f,0.f},{0.f,0.f,0.f,0.f}};
  bf16x8 pbh = *(const bf16x8*)(cthi + feat * K_CLUSTERS + quad * 8);
  bf16x8 pbl = *(const bf16x8*)(ctlo + feat * K_CLUSTERS + quad * 8);
#pragma unroll
  for (int ks = 0; ks < 16; ++ks) {
    bf16x8 bh = pbh, bl = pbl;
    if (ks < 15) {
      pbh = *(const bf16x8*)(cthi + feat * K_CLUSTERS + (ks + 1) * 32 + quad * 8);
      pbl = *(const bf16x8*)(ctlo + feat * K_CLUSTERS + (ks + 1) * 32 + quad * 8);
    }
    const int ac = ks * 32 + quad * 8;
#pragma unroll
    for (int rt = 0; rt < 4; ++rt) {
      int arow = rt * 16 + l16;
      bf16x8 aw = *(const bf16x8*)(W + arow * 512 +
                                   (ac ^ ((((unsigned)arow >> 2) & 3) << 4)));
      oacc[rt] = __builtin_amdgcn_mfma_f32_16x16x32_bf16(aw, bh, oacc[rt], 0, 0, 0);
      oacc[rt] = __builtin_amdgcn_mfma_f32_16x16x32_bf16(aw, bl, oacc[rt], 0, 0, 0);
    }
  }

  // ---- epilogue: normalize, store ----
#pragma unroll
  for (int rt = 0; rt < 4; ++rt) {
    float* obase = out + (rowbase + rt * 16) * D_FEAT + feat;
#pragma unroll
    for (int r = 0; r < 4; ++r)
      obase[(quad * 4 + r) * D_FEAT] = oacc[rt][r] * inv[rt][r];
  }
}

extern "C" void kernel_launch(void* const* d_in, const int* in_sizes, int n_in,
                              void* d_out, int out_size, void* d_ws, size_t ws_size,
                              hipStream_t stream) {
  const float* x    = (const float*)d_in[0];
  const float* cent = (const float*)d_in[1];
  float* out        = (float*)d_out;

  unsigned short* chi  = (unsigned short*)d_ws;
  unsigned short* clo  = chi  + K_CLUSTERS * D_FEAT;
  unsigned short* cthi = clo  + K_CLUSTERS * D_FEAT;
  unsigned short* ctlo = cthi + K_CLUSTERS * D_FEAT;
  float*          csqs = (float*)(ctlo + K_CLUSTERS * D_FEAT);

  kmeans_prep<<<(K_CLUSTERS + THREADS - 1) / THREADS, THREADS, 0, stream>>>(
      cent, chi, clo, cthi, ctlo, csqs);

  int nrows = in_sizes[0] / D_FEAT;  // 131072
  kmeans_main<<<nrows / ROWS_PER_BLOCK, THREADS, 0, stream>>>(
      x, chi, clo, cthi, ctlo, csqs, out);
}

// Round 4
// 140.760 us; speedup vs baseline: 2.2769x; 1.0838x over previous
//
#include <hip/hip_runtime.h>

#define K_CLUSTERS 512
#define D_FEAT 64
#define ROWS_PER_BLOCK 64
#define THREADS 256

typedef short bf16x8 __attribute__((ext_vector_type(8)));
typedef short bf16x4 __attribute__((ext_vector_type(4)));
typedef float f32x4 __attribute__((ext_vector_type(4)));

__device__ __forceinline__ unsigned short f32_to_bf16(float f) {
  unsigned int u = __float_as_uint(f);
  u += 0x7fffu + ((u >> 16) & 1u);   // RNE
  return (unsigned short)(u >> 16);
}
__device__ __forceinline__ float bf16_to_f32(unsigned short h) {
  return __uint_as_float(((unsigned int)h) << 16);
}

// W swizzle: element cx = c ^ ((row&7)<<3). 8-elem chunks keyed on row so the
// Phase-C b128 reads (16 lanes = 16 rows, same 8-elem chunk base) spread over
// all 32 banks at 2 lanes/bank (free); Phase-A b16 scatter writes merge within
// dwords and stay <=2-way.
#define WSWZ(row) ((((unsigned)(row)) & 7u) << 3)

// ---------------- prep: one wave per cluster, lane = feature. Coalesced.
__global__ void kmeans_prep(const float* __restrict__ cent,
                            unsigned short* __restrict__ chi,   // [K][D]
                            unsigned short* __restrict__ clo,   // [K][D]
                            unsigned short* __restrict__ cthi,  // [D][K]
                            unsigned short* __restrict__ ctlo,  // [D][K]
                            float* __restrict__ csqs) {         // [K], 10*log2e*|c|^2
  const int wv = threadIdx.x >> 6;
  const int lane = threadIdx.x & 63;
  const int k = blockIdx.x * 4 + wv;    // grid = 128 blocks -> k in [0,512)
  const int f = lane;
  float v = cent[k * D_FEAT + f];
  unsigned short h = f32_to_bf16(v);
  float rem = v - bf16_to_f32(h);
  unsigned short l = f32_to_bf16(rem);
  chi[k * D_FEAT + f] = h;
  clo[k * D_FEAT + f] = l;
  cthi[f * K_CLUSTERS + k] = h;
  ctlo[f * K_CLUSTERS + k] = l;
  float s = v * v;
#pragma unroll
  for (int d = 1; d < 64; d <<= 1) s += __shfl_xor(s, d, 64);
  if (lane == 0) csqs[k] = s * 14.42695040888963f;  // 10 * log2(e)
}

// ---------------- main fused kernel: 64 rows/block.
// Phase A: cluster-split (wave owns 128 clusters, all 4 row-tiles), depth-2
// prefetch, weights exp'd + streamed to swizzled LDS (no max pass: logits
// bounded, |logit| < ~80 in exp2 domain).
// Phase C: feature-split (wave owns 16 feats), W from LDS, depth-2 prefetch.
__global__ __launch_bounds__(THREADS, 2) void kmeans_main(
    const float* __restrict__ x,
    const unsigned short* __restrict__ chi,
    const unsigned short* __restrict__ clo,
    const unsigned short* __restrict__ cthi,
    const unsigned short* __restrict__ ctlo,
    const float* __restrict__ csqs,
    float* __restrict__ out) {
  // LDS: W [64][512] bf16 (65536 B, swizzled) + redsum [64][4] f32.
  // x staging xh/xl [64][72] (18432 B) aliases head of W (dead after A-frag
  // loads, fenced by barrier 2).
  __shared__ __attribute__((aligned(16))) unsigned char smem[65536 + 1024];
  unsigned short* xh = (unsigned short*)smem;            // [64][72]
  unsigned short* xl = xh + 64 * 72;                     // [64][72]
  unsigned short* W  = (unsigned short*)smem;            // [64][512] swizzled
  float* redsum = (float*)(smem + 65536);                // [64][4]

  const int tid  = threadIdx.x;
  const int wv   = tid >> 6;
  const int lane = tid & 63;
  const int l16  = lane & 15;
  const int quad = lane >> 4;
  const long long rowbase = (long long)blockIdx.x * ROWS_PER_BLOCK;

  // ---- stage x -> xh/xl (coalesced float4 loads, hi/lo bf16 split) ----
  {
    int r  = tid >> 2;             // 0..63
    int f0 = (tid & 3) * 16;       // 0,16,32,48
    const float4* src4 = (const float4*)(x + (rowbase + r) * D_FEAT + f0);
#pragma unroll
    for (int i = 0; i < 4; ++i) {
      float4 v = src4[i];
      float vv[4] = {v.x, v.y, v.z, v.w};
      bf16x4 hi, lo;
#pragma unroll
      for (int j = 0; j < 4; ++j) {
        unsigned short h = f32_to_bf16(vv[j]);
        hi[j] = (short)h;
        lo[j] = (short)f32_to_bf16(vv[j] - bf16_to_f32(h));
      }
      *(bf16x4*)(xh + r * 72 + f0 + i * 4) = hi;
      *(bf16x4*)(xl + r * 72 + f0 + i * 4) = lo;
    }
  }
  __syncthreads();   // staging visible

  // ---- A fragments for all 4 row-tiles: A[m=l16][k=quad*8+j], 64 VGPRs ----
  bf16x8 ah[4][2], al[4][2];
#pragma unroll
  for (int rt = 0; rt < 4; ++rt)
#pragma unroll
    for (int ks = 0; ks < 2; ++ks) {
      ah[rt][ks] = *(const bf16x8*)(xh + (rt * 16 + l16) * 72 + ks * 32 + quad * 8);
      al[rt][ks] = *(const bf16x8*)(xl + (rt * 16 + l16) * 72 + ks * 32 + quad * 8);
    }
  __syncthreads();   // xh/xl dead -> W region writable

  // ---- Phase A: wave's 128-cluster slice x 64 rows, depth-2 prefetch ----
  const int cbase = wv * 128;
  const int bko = quad * 8;
  f32x4 srow[4] = {{0.f,0.f,0.f,0.f},{0.f,0.f,0.f,0.f},{0.f,0.f,0.f,0.f},{0.f,0.f,0.f,0.f}};

  bf16x8 pbh0[2], pbh1[2], pbl0[2], pbl1[2];
  float pcs[2];
#pragma unroll
  for (int p = 0; p < 2; ++p) {
    int cl = cbase + p * 16 + l16;
    pbh0[p] = *(const bf16x8*)(chi + cl * 64 + bko);
    pbh1[p] = *(const bf16x8*)(chi + cl * 64 + 32 + bko);
    pbl0[p] = *(const bf16x8*)(clo + cl * 64 + bko);
    pbl1[p] = *(const bf16x8*)(clo + cl * 64 + 32 + bko);
    pcs[p]  = csqs[cl];
  }

#pragma unroll
  for (int t = 0; t < 8; ++t) {
    const int sl = t & 1;
    bf16x8 cbh0 = pbh0[sl], cbh1 = pbh1[sl], cbl0 = pbl0[sl], cbl1 = pbl1[sl];
    float ccs = pcs[sl];
    if (t < 6) {   // prefetch t+2
      int cl = cbase + (t + 2) * 16 + l16;
      pbh0[sl] = *(const bf16x8*)(chi + cl * 64 + bko);
      pbh1[sl] = *(const bf16x8*)(chi + cl * 64 + 32 + bko);
      pbl0[sl] = *(const bf16x8*)(clo + cl * 64 + bko);
      pbl1[sl] = *(const bf16x8*)(clo + cl * 64 + 32 + bko);
      pcs[sl]  = csqs[cl];
    }
    const int c = cbase + t * 16 + l16;
#pragma unroll
    for (int rt = 0; rt < 4; ++rt) {
      f32x4 a = {0.f, 0.f, 0.f, 0.f};
      a = __builtin_amdgcn_mfma_f32_16x16x32_bf16(ah[rt][0], cbh0, a, 0, 0, 0);
      a = __builtin_amdgcn_mfma_f32_16x16x32_bf16(ah[rt][1], cbh1, a, 0, 0, 0);
      a = __builtin_amdgcn_mfma_f32_16x16x32_bf16(ah[rt][0], cbl0, a, 0, 0, 0);
      a = __builtin_amdgcn_mfma_f32_16x16x32_bf16(ah[rt][1], cbl1, a, 0, 0, 0);
      a = __builtin_amdgcn_mfma_f32_16x16x32_bf16(al[rt][0], cbh0, a, 0, 0, 0);
      a = __builtin_amdgcn_mfma_f32_16x16x32_bf16(al[rt][1], cbh1, a, 0, 0, 0);
      // weight = 2^(20*log2e*cross - 10*log2e*|c|^2); row const cancels
#pragma unroll
      for (int r = 0; r < 4; ++r) {
        float e = exp2f(fmaf(28.85390081777927f, a[r], -ccs));
        srow[rt][r] += e;
        int row = rt * 16 + quad * 4 + r;
        W[row * 512 + ((unsigned)c ^ WSWZ(row))] = f32_to_bf16(e);
      }
    }
  }

  // ---- per-wave partial row sums -> LDS ----
#pragma unroll
  for (int d = 1; d < 16; d <<= 1)
#pragma unroll
    for (int rt = 0; rt < 4; ++rt)
#pragma unroll
      for (int r = 0; r < 4; ++r) srow[rt][r] += __shfl_xor(srow[rt][r], d, 64);
  if (l16 == 0) {
#pragma unroll
    for (int rt = 0; rt < 4; ++rt)
#pragma unroll
      for (int r = 0; r < 4; ++r)
        redsum[(rt * 16 + quad * 4 + r) * 4 + wv] = srow[rt][r];
  }
  __syncthreads();   // W + redsum visible to all waves

  // ---- reciprocal row sums (broadcast LDS reads) ----
  float inv[4][4];
#pragma unroll
  for (int rt = 0; rt < 4; ++rt)
#pragma unroll
    for (int r = 0; r < 4; ++r) {
      f32x4 s4 = *(const f32x4*)(redsum + (rt * 16 + quad * 4 + r) * 4);
      inv[rt][r] = __builtin_amdgcn_rcpf((s4[0] + s4[1]) + (s4[2] + s4[3]));
    }

  // ---- Phase C: wave's 16-feature slice, full K=512, depth-2 prefetch ----
  const int feat = wv * 16 + l16;
  const unsigned short* cth = cthi + feat * K_CLUSTERS;
  const unsigned short* ctl = ctlo + feat * K_CLUSTERS;
  f32x4 oacc[4] = {{0.f,0.f,0.f,0.f},{0.f,0.f,0.f,0.f},{0.f,0.f,0.f,0.f},{0.f,0.f,0.f,0.f}};

  bf16x8 qbh[2], qbl[2];
#pragma unroll
  for (int p = 0; p < 2; ++p) {
    qbh[p] = *(const bf16x8*)(cth + p * 32 + quad * 8);
    qbl[p] = *(const bf16x8*)(ctl + p * 32 + quad * 8);
  }
#pragma unroll
  for (int ks = 0; ks < 16; ++ks) {
    const int sl = ks & 1;
    bf16x8 bh = qbh[sl], bl = qbl[sl];
    if (ks < 14) {   // prefetch ks+2
      qbh[sl] = *(const bf16x8*)(cth + (ks + 2) * 32 + quad * 8);
      qbl[sl] = *(const bf16x8*)(ctl + (ks + 2) * 32 + quad * 8);
    }
    const int ac = ks * 32 + quad * 8;
#pragma unroll
    for (int rt = 0; rt < 4; ++rt) {
      int arow = rt * 16 + l16;
      bf16x8 aw = *(const bf16x8*)(W + arow * 512 + ((unsigned)ac ^ WSWZ(arow)));
      oacc[rt] = __builtin_amdgcn_mfma_f32_16x16x32_bf16(aw, bh, oacc[rt], 0, 0, 0);
      oacc[rt] = __builtin_amdgcn_mfma_f32_16x16x32_bf16(aw, bl, oacc[rt], 0, 0, 0);
    }
  }

  // ---- epilogue: normalize, store ----
#pragma unroll
  for (int rt = 0; rt < 4; ++rt) {
    float* obase = out + (rowbase + rt * 16) * D_FEAT + feat;
#pragma unroll
    for (int r = 0; r < 4; ++r)
      obase[(quad * 4 + r) * D_FEAT] = oacc[rt][r] * inv[rt][r];
  }
}

extern "C" void kernel_launch(void* const* d_in, const int* in_sizes, int n_in,
                              void* d_out, int out_size, void* d_ws, size_t ws_size,
                              hipStream_t stream) {
  const float* x    = (const float*)d_in[0];
  const float* cent = (const float*)d_in[1];
  float* out        = (float*)d_out;

  unsigned short* chi  = (unsigned short*)d_ws;
  unsigned short* clo  = chi  + K_CLUSTERS * D_FEAT;
  unsigned short* cthi = clo  + K_CLUSTERS * D_FEAT;
  unsigned short* ctlo = cthi + K_CLUSTERS * D_FEAT;
  float*          csqs = (float*)(ctlo + K_CLUSTERS * D_FEAT);

  kmeans_prep<<<K_CLUSTERS / 4, THREADS, 0, stream>>>(
      cent, chi, clo, cthi, ctlo, csqs);

  int nrows = in_sizes[0] / D_FEAT;  // 131072
  kmeans_main<<<nrows / ROWS_PER_BLOCK, THREADS, 0, stream>>>(
      x, chi, clo, cthi, ctlo, csqs, out);
}